// Round 3
// baseline (418.891 us; speedup 1.0000x reference)
//
#include <hip/hip_runtime.h>

#define D 128

// ---------------------------------------------------------------------------
// prep: Wt[k][j] = (k<128 ? W1[j][k] : W2[j][k-128]);  bsum[j] = b1[j]+b2[j]
// ---------------------------------------------------------------------------
__global__ __launch_bounds__(256) void prep_k(
    const float* __restrict__ W1, const float* __restrict__ b1,
    const float* __restrict__ W2, const float* __restrict__ b2,
    float* __restrict__ Wt, float* __restrict__ bsum) {
  int tid = blockIdx.x * 256 + threadIdx.x;
  if (tid < 256 * 128) {
    int k = tid >> 7, j = tid & 127;
    float v = (k < 128) ? W1[j * 128 + k] : W2[j * 128 + (k - 128)];
    Wt[tid] = v;
  }
  if (tid < 128) bsum[tid] = b1[tid] + b2[tid];
}

// ---------------------------------------------------------------------------
// CSR build: histogram -> 3-kernel exclusive scan -> fill (bucket edges by col)
// ---------------------------------------------------------------------------
__global__ __launch_bounds__(256) void hist_k(
    const int* __restrict__ ei, int* __restrict__ cursor, int E) {
  int e = blockIdx.x * 256 + threadIdx.x;
  if (e < E) atomicAdd(&cursor[ei[E + e]], 1);
}

__global__ __launch_bounds__(256) void scan_block_k(
    const int* __restrict__ deg, int* __restrict__ rowptr,
    int* __restrict__ partials, int Nn) {
  __shared__ int sdata[256];
  int t = threadIdx.x;
  int base = blockIdx.x * 1024 + t * 4;
  int v[4];
  #pragma unroll
  for (int j = 0; j < 4; ++j) v[j] = (base + j < Nn) ? deg[base + j] : 0;
  int tsum = v[0] + v[1] + v[2] + v[3];
  sdata[t] = tsum;
  __syncthreads();
  for (int off = 1; off < 256; off <<= 1) {
    int add = (t >= off) ? sdata[t - off] : 0;
    __syncthreads();
    sdata[t] += add;
    __syncthreads();
  }
  int run = sdata[t] - tsum;
  if (t == 255) partials[blockIdx.x] = sdata[255];
  #pragma unroll
  for (int j = 0; j < 4; ++j) {
    if (base + j < Nn) rowptr[base + j] = run;
    run += v[j];
  }
}

__global__ __launch_bounds__(128) void scan_partials_k(int* partials, int NB) {
  __shared__ int s[128];
  int t = threadIdx.x;
  int orig = (t < NB) ? partials[t] : 0;
  s[t] = orig;
  __syncthreads();
  for (int off = 1; off < 128; off <<= 1) {
    int add = (t >= off) ? s[t - off] : 0;
    __syncthreads();
    s[t] += add;
    __syncthreads();
  }
  if (t < NB) partials[t] = s[t] - orig;
}

__global__ __launch_bounds__(256) void add_offsets_k(
    int* __restrict__ rowptr, int* __restrict__ cursor,
    const int* __restrict__ partials, int Nn, int E) {
  int i = blockIdx.x * 256 + threadIdx.x;
  if (i < Nn) {
    int v = rowptr[i] + partials[i >> 10];
    rowptr[i] = v;
    cursor[i] = v;
  }
  if (i == 0) rowptr[Nn] = E;
}

__global__ __launch_bounds__(256) void fill_k(
    const int* __restrict__ ei, const float* __restrict__ ew,
    int* __restrict__ cursor, int* __restrict__ srcRow,
    float* __restrict__ srcW, int E) {
  int e = blockIdx.x * 256 + threadIdx.x;
  if (e >= E) return;
  int c = ei[E + e];
  int p = atomicAdd(&cursor[c], 1);
  srcRow[p] = ei[e];
  srcW[p] = ew[e];
}

// ---------------------------------------------------------------------------
// aggregate: one wave per node, lane owns float2. 8 gathers in flight.
// ---------------------------------------------------------------------------
__global__ __launch_bounds__(256) void agg_k(
    const float* __restrict__ x, const int* __restrict__ rowptr,
    const int* __restrict__ srcRow, const float* __restrict__ srcW,
    float* __restrict__ agg, int Nn) {
  int node = blockIdx.x * 4 + (threadIdx.x >> 6);
  if (node >= Nn) return;
  int lane = threadIdx.x & 63;
  int beg = rowptr[node], end = rowptr[node + 1];
  float2 acc = make_float2(0.f, 0.f);
  int p = beg;
  for (; p + 8 <= end; p += 8) {
    int r[8];
    float w[8];
    #pragma unroll
    for (int i = 0; i < 8; ++i) { r[i] = srcRow[p + i]; w[i] = srcW[p + i]; }
    float2 v[8];
    #pragma unroll
    for (int i = 0; i < 8; ++i)
      v[i] = ((const float2*)(x + (size_t)r[i] * D))[lane];
    #pragma unroll
    for (int i = 0; i < 8; ++i) {
      acc.x += w[i] * v[i].x;
      acc.y += w[i] * v[i].y;
    }
  }
  for (; p + 4 <= end; p += 4) {
    int r0 = srcRow[p], r1 = srcRow[p + 1], r2 = srcRow[p + 2], r3 = srcRow[p + 3];
    float w0 = srcW[p], w1 = srcW[p + 1], w2 = srcW[p + 2], w3 = srcW[p + 3];
    float2 v0 = ((const float2*)(x + (size_t)r0 * D))[lane];
    float2 v1 = ((const float2*)(x + (size_t)r1 * D))[lane];
    float2 v2 = ((const float2*)(x + (size_t)r2 * D))[lane];
    float2 v3 = ((const float2*)(x + (size_t)r3 * D))[lane];
    acc.x += w0 * v0.x; acc.y += w0 * v0.y;
    acc.x += w1 * v1.x; acc.y += w1 * v1.y;
    acc.x += w2 * v2.x; acc.y += w2 * v2.y;
    acc.x += w3 * v3.x; acc.y += w3 * v3.y;
  }
  for (; p < end; ++p) {
    int r = srcRow[p];
    float w = srcW[p];
    float2 v = ((const float2*)(x + (size_t)r * D))[lane];
    acc.x += w * v.x; acc.y += w * v.y;
  }
  ((float2*)(agg + (size_t)node * D))[lane] = acc;
}

// ---------------------------------------------------------------------------
// fused: 32-node tile (33.8 KB LDS -> 4 blocks/CU, 16 waves/CU).
// Thread: 2 nodes x 8 outputs.
// ---------------------------------------------------------------------------
__global__ __launch_bounds__(256, 4) void fused_k(
    const float* __restrict__ x, const float* __restrict__ agg,
    const float* __restrict__ Wt, const float* __restrict__ bsum,
    float* __restrict__ out, int Nn) {
  constexpr int STR = 264;
  __shared__ float U[32 * STR];
  const int t = threadIdx.x;
  const int node0 = blockIdx.x * 32;

  #pragma unroll
  for (int i = 0; i < 4; ++i) {
    int f4 = t + i * 256;          // 0..1023
    int node = f4 >> 5;
    int d4 = f4 & 31;
    int g = node0 + node;
    float4 a4 = make_float4(0.f, 0.f, 0.f, 0.f), x4 = a4;
    if (g < Nn) {
      a4 = ((const float4*)agg)[(size_t)g * 32 + d4];
      x4 = ((const float4*)x)[(size_t)g * 32 + d4];
    }
    float4 u4 = make_float4(a4.x + x4.x, a4.y + x4.y, a4.z + x4.z, a4.w + x4.w);
    float4 v4 = make_float4(a4.x * x4.x, a4.y * x4.y, a4.z * x4.z, a4.w * x4.w);
    *(float4*)&U[node * STR + d4 * 4]       = u4;
    *(float4*)&U[node * STR + 128 + d4 * 4] = v4;
  }
  __syncthreads();

  const int tx = t & 15, ty = t >> 4;
  const int j0 = tx * 8;
  float acc[2][8];
  #pragma unroll
  for (int m = 0; m < 2; ++m)
    #pragma unroll
    for (int j = 0; j < 8; ++j) acc[m][j] = 0.f;

  const float* ub = &U[(ty * 2) * STR];
  for (int k = 0; k < 256; k += 4) {
    float a[2][4];
    #pragma unroll
    for (int m = 0; m < 2; ++m)
      *(float4*)a[m] = *(const float4*)(ub + m * STR + k);
    #pragma unroll
    for (int kk = 0; kk < 4; ++kk) {
      const float* wrow = Wt + (k + kk) * 128 + j0;
      float4 bA = *(const float4*)(wrow);
      float4 bB = *(const float4*)(wrow + 4);
      float bb[8] = {bA.x, bA.y, bA.z, bA.w, bB.x, bB.y, bB.z, bB.w};
      #pragma unroll
      for (int m = 0; m < 2; ++m) {
        float av = a[m][kk];
        #pragma unroll
        for (int j = 0; j < 8; ++j) acc[m][j] += av * bb[j];
      }
    }
  }

  float bs[8];
  *(float4*)&bs[0] = *(const float4*)(bsum + j0);
  *(float4*)&bs[4] = *(const float4*)(bsum + j0 + 4);
  #pragma unroll
  for (int m = 0; m < 2; ++m) {
    int g = node0 + ty * 2 + m;
    if (g >= Nn) continue;
    float r[8];
    #pragma unroll
    for (int j = 0; j < 8; ++j) {
      float h = acc[m][j] + bs[j];
      r[j] = h > 0.f ? h : 0.2f * h;
    }
    ((float4*)out)[(size_t)g * 32 + (j0 >> 2)]     = *(float4*)&r[0];
    ((float4*)out)[(size_t)g * 32 + (j0 >> 2) + 1] = *(float4*)&r[4];
  }
}

// ---------------------------------------------------------------------------
extern "C" void kernel_launch(void* const* d_in, const int* in_sizes, int n_in,
                              void* d_out, int out_size, void* d_ws, size_t ws_size,
                              hipStream_t stream) {
  const float* x  = (const float*)d_in[0];
  const int*   ei = (const int*)d_in[1];
  const float* ew = (const float*)d_in[2];
  const float* W1 = (const float*)d_in[3];
  const float* b1 = (const float*)d_in[4];
  const float* W2 = (const float*)d_in[5];
  const float* b2 = (const float*)d_in[6];
  float* out = (float*)d_out;

  const int Nn = in_sizes[0] / D;   // 100000
  const int E  = in_sizes[2];       // 600000
  const int NB = (Nn + 1023) / 1024;

  const size_t aggB    = (size_t)Nn * D * sizeof(float);
  const size_t srcRowB = (size_t)E * sizeof(int);
  const size_t srcWB   = (size_t)E * sizeof(float);
  const size_t cursorB = (size_t)Nn * sizeof(int);
  const size_t rowptrB = (((size_t)(Nn + 1) * sizeof(int)) + 15) & ~(size_t)15;
  const size_t partB   = 1024;
  const size_t WtB     = 256 * 128 * sizeof(float);
  const size_t bsB     = 512;
  const size_t smallB  = srcRowB + srcWB + cursorB + rowptrB + partB + WtB + bsB;

  char* base = (char*)d_ws;
  float* agg;
  if (ws_size >= aggB + smallB) {
    agg = (float*)base;
    base += aggB;
  } else {
    agg = out;  // safe fallback: fused_k reads its own tile rows before writing
  }
  int*   srcRow  = (int*)base;                base += srcRowB;
  float* srcW    = (float*)base;              base += srcWB;
  int*   cursor  = (int*)base;                base += cursorB;
  int*   rowptr  = (int*)base;                base += rowptrB;
  int*   partials= (int*)base;                base += partB;
  float* Wt      = (float*)base;              base += WtB;
  float* bs      = (float*)base;

  hipMemsetAsync(cursor, 0, cursorB, stream);
  int eBlocks = (E + 255) / 256;
  hist_k<<<eBlocks, 256, 0, stream>>>(ei, cursor, E);
  scan_block_k<<<NB, 256, 0, stream>>>(cursor, rowptr, partials, Nn);
  scan_partials_k<<<1, 128, 0, stream>>>(partials, NB);
  add_offsets_k<<<(Nn + 255) / 256, 256, 0, stream>>>(rowptr, cursor, partials, Nn, E);
  fill_k<<<eBlocks, 256, 0, stream>>>(ei, ew, cursor, srcRow, srcW, E);

  prep_k<<<128, 256, 0, stream>>>(W1, b1, W2, b2, Wt, bs);

  agg_k<<<(Nn + 3) / 4, 256, 0, stream>>>(x, rowptr, srcRow, srcW, agg, Nn);

  fused_k<<<(Nn + 31) / 32, 256, 0, stream>>>(x, agg, Wt, bs, out, Nn);
}

// Round 4
// 352.226 us; speedup vs baseline: 1.1893x; 1.1893x over previous
//
#include <hip/hip_runtime.h>

#define D 128

__device__ __forceinline__ unsigned int f2bf(float f) {
  unsigned int u = __float_as_uint(f);
  return (u + 0x7fffu + ((u >> 16) & 1u)) >> 16;   // RNE to bf16
}

// ---------------------------------------------------------------------------
// prep: Wt[k][j] = (k<128 ? W1[j][k] : W2[j][k-128]);  bsum[j] = b1[j]+b2[j]
// ---------------------------------------------------------------------------
__global__ __launch_bounds__(256) void prep_k(
    const float* __restrict__ W1, const float* __restrict__ b1,
    const float* __restrict__ W2, const float* __restrict__ b2,
    float* __restrict__ Wt, float* __restrict__ bsum) {
  int tid = blockIdx.x * 256 + threadIdx.x;
  if (tid < 256 * 128) {
    int k = tid >> 7, j = tid & 127;
    float v = (k < 128) ? W1[j * 128 + k] : W2[j * 128 + (k - 128)];
    Wt[tid] = v;
  }
  if (tid < 128) bsum[tid] = b1[tid] + b2[tid];
}

// ---------------------------------------------------------------------------
// CSR build
// ---------------------------------------------------------------------------
__global__ __launch_bounds__(256) void hist_k(
    const int* __restrict__ ei, int* __restrict__ cursor, int E) {
  int e = blockIdx.x * 256 + threadIdx.x;
  if (e < E) atomicAdd(&cursor[ei[E + e]], 1);
}

__global__ __launch_bounds__(256) void scan_block_k(
    const int* __restrict__ deg, int* __restrict__ rowptr,
    int* __restrict__ partials, int Nn) {
  __shared__ int sdata[256];
  int t = threadIdx.x;
  int base = blockIdx.x * 1024 + t * 4;
  int v[4];
  #pragma unroll
  for (int j = 0; j < 4; ++j) v[j] = (base + j < Nn) ? deg[base + j] : 0;
  int tsum = v[0] + v[1] + v[2] + v[3];
  sdata[t] = tsum;
  __syncthreads();
  for (int off = 1; off < 256; off <<= 1) {
    int add = (t >= off) ? sdata[t - off] : 0;
    __syncthreads();
    sdata[t] += add;
    __syncthreads();
  }
  int run = sdata[t] - tsum;
  if (t == 255) partials[blockIdx.x] = sdata[255];
  #pragma unroll
  for (int j = 0; j < 4; ++j) {
    if (base + j < Nn) rowptr[base + j] = run;
    run += v[j];
  }
}

__global__ __launch_bounds__(128) void scan_partials_k(int* partials, int NB) {
  __shared__ int s[128];
  int t = threadIdx.x;
  int orig = (t < NB) ? partials[t] : 0;
  s[t] = orig;
  __syncthreads();
  for (int off = 1; off < 128; off <<= 1) {
    int add = (t >= off) ? s[t - off] : 0;
    __syncthreads();
    s[t] += add;
    __syncthreads();
  }
  if (t < NB) partials[t] = s[t] - orig;
}

__global__ __launch_bounds__(256) void add_offsets_k(
    int* __restrict__ rowptr, int* __restrict__ cursor,
    const int* __restrict__ partials, int Nn, int E) {
  int i = blockIdx.x * 256 + threadIdx.x;
  if (i < Nn) {
    int v = rowptr[i] + partials[i >> 10];
    rowptr[i] = v;
    cursor[i] = v;
  }
  if (i == 0) rowptr[Nn] = E;
}

__global__ __launch_bounds__(256) void fill_k(
    const int* __restrict__ ei, const float* __restrict__ ew,
    int* __restrict__ cursor, int2* __restrict__ edges, int E) {
  int e = blockIdx.x * 256 + threadIdx.x;
  if (e >= E) return;
  int c = ei[E + e];
  int p = atomicAdd(&cursor[c], 1);
  edges[p] = make_int2(ei[e], __float_as_int(ew[e]));
}

// ---------------------------------------------------------------------------
// aggregate: one wave per node, lane owns float2. Branchless 8-deep batch
// (index-clamped, weight-masked) so small-degree nodes issue all gathers at
// once instead of a serialized tail.
// ---------------------------------------------------------------------------
__global__ __launch_bounds__(256) void agg_k(
    const float* __restrict__ x, const int* __restrict__ rowptr,
    const int2* __restrict__ edges, float* __restrict__ agg, int Nn) {
  int node = blockIdx.x * 4 + (threadIdx.x >> 6);
  if (node >= Nn) return;
  int lane = threadIdx.x & 63;
  int beg = rowptr[node], end = rowptr[node + 1];
  float2 acc = make_float2(0.f, 0.f);
  for (int p = beg; p < end; p += 8) {
    int n = end - p;  // >=1
    int2 e[8];
    #pragma unroll
    for (int i = 0; i < 8; ++i) e[i] = edges[min(p + i, end - 1)];
    float2 v[8];
    #pragma unroll
    for (int i = 0; i < 8; ++i)
      v[i] = ((const float2*)(x + (size_t)e[i].x * D))[lane];
    #pragma unroll
    for (int i = 0; i < 8; ++i) {
      float w = (i < n) ? __int_as_float(e[i].y) : 0.f;
      acc.x += w * v[i].x;
      acc.y += w * v[i].y;
    }
  }
  ((float2*)(agg + (size_t)node * D))[lane] = acc;
}

// ---------------------------------------------------------------------------
// fused: u=agg+x, v=agg*x staged in LDS as bf16 (RNE); h=[u,v]@Wt(f32)+bsum;
// leakyrelu. 64-node tile, 33.5 KB LDS -> 4 blocks/CU. Thread: 4 nodes x 8 j.
// Row stride 536 B: the 4 ty-rows of a wave hit banks {0,24,16,8} -> no
// conflict on ds_read_b64.
// ---------------------------------------------------------------------------
__global__ __launch_bounds__(256, 4) void fused_k(
    const float* __restrict__ x, const float* __restrict__ agg,
    const float* __restrict__ Wt, const float* __restrict__ bsum,
    float* __restrict__ out, int Nn) {
  constexpr int ROWB = 536;                 // 256 bf16 (512 B) + 24 B pad
  __shared__ __align__(16) unsigned char Us[64 * ROWB];
  const int t = threadIdx.x;
  const int node0 = blockIdx.x * 64;

  #pragma unroll
  for (int i = 0; i < 8; ++i) {
    int f4 = t + i * 256;                   // 0..2047
    int node = f4 >> 5;                     // 32 float4 per node
    int d4 = f4 & 31;
    int g = node0 + node;
    float4 a4 = make_float4(0.f, 0.f, 0.f, 0.f), x4 = a4;
    if (g < Nn) {
      a4 = ((const float4*)agg)[(size_t)g * 32 + d4];
      x4 = ((const float4*)x)[(size_t)g * 32 + d4];
    }
    float u0 = a4.x + x4.x, u1 = a4.y + x4.y, u2 = a4.z + x4.z, u3 = a4.w + x4.w;
    float v0 = a4.x * x4.x, v1 = a4.y * x4.y, v2 = a4.z * x4.z, v3 = a4.w * x4.w;
    uint2 up, vp;
    up.x = f2bf(u0) | (f2bf(u1) << 16);
    up.y = f2bf(u2) | (f2bf(u3) << 16);
    vp.x = f2bf(v0) | (f2bf(v1) << 16);
    vp.y = f2bf(v2) | (f2bf(v3) << 16);
    *(uint2*)(Us + node * ROWB + d4 * 8)       = up;   // u: bytes [0,256)
    *(uint2*)(Us + node * ROWB + 256 + d4 * 8) = vp;   // v: bytes [256,512)
  }
  __syncthreads();

  const int tx = t & 15, ty = t >> 4;
  const int j0 = tx * 8;
  float acc[4][8];
  #pragma unroll
  for (int m = 0; m < 4; ++m)
    #pragma unroll
    for (int j = 0; j < 8; ++j) acc[m][j] = 0.f;

  const unsigned char* ub = Us + (ty * 4) * ROWB;
  for (int k = 0; k < 256; k += 4) {
    uint2 d[4];
    #pragma unroll
    for (int m = 0; m < 4; ++m)
      d[m] = *(const uint2*)(ub + m * ROWB + k * 2);   // 4 bf16 of row
    #pragma unroll
    for (int kk = 0; kk < 4; ++kk) {
      const float* wrow = Wt + (k + kk) * 128 + j0;
      float4 bA = *(const float4*)(wrow);
      float4 bB = *(const float4*)(wrow + 4);
      float bb[8] = {bA.x, bA.y, bA.z, bA.w, bB.x, bB.y, bB.z, bB.w};
      #pragma unroll
      for (int m = 0; m < 4; ++m) {
        unsigned int w = (kk < 2) ? d[m].x : d[m].y;
        float av = __uint_as_float((kk & 1) ? (w & 0xffff0000u) : (w << 16));
        #pragma unroll
        for (int j = 0; j < 8; ++j) acc[m][j] += av * bb[j];
      }
    }
  }

  float bs[8];
  *(float4*)&bs[0] = *(const float4*)(bsum + j0);
  *(float4*)&bs[4] = *(const float4*)(bsum + j0 + 4);
  #pragma unroll
  for (int m = 0; m < 4; ++m) {
    int g = node0 + ty * 4 + m;
    if (g >= Nn) continue;
    float r[8];
    #pragma unroll
    for (int j = 0; j < 8; ++j) {
      float h = acc[m][j] + bs[j];
      r[j] = h > 0.f ? h : 0.2f * h;
    }
    ((float4*)out)[(size_t)g * 32 + (j0 >> 2)]     = *(float4*)&r[0];
    ((float4*)out)[(size_t)g * 32 + (j0 >> 2) + 1] = *(float4*)&r[4];
  }
}

// ---------------------------------------------------------------------------
extern "C" void kernel_launch(void* const* d_in, const int* in_sizes, int n_in,
                              void* d_out, int out_size, void* d_ws, size_t ws_size,
                              hipStream_t stream) {
  const float* x  = (const float*)d_in[0];
  const int*   ei = (const int*)d_in[1];
  const float* ew = (const float*)d_in[2];
  const float* W1 = (const float*)d_in[3];
  const float* b1 = (const float*)d_in[4];
  const float* W2 = (const float*)d_in[5];
  const float* b2 = (const float*)d_in[6];
  float* out = (float*)d_out;

  const int Nn = in_sizes[0] / D;   // 100000
  const int E  = in_sizes[2];       // 600000
  const int NB = (Nn + 1023) / 1024;

  const size_t aggB    = (size_t)Nn * D * sizeof(float);
  const size_t edgesB  = (size_t)E * sizeof(int2);
  const size_t cursorB = (size_t)Nn * sizeof(int);
  const size_t rowptrB = (((size_t)(Nn + 1) * sizeof(int)) + 15) & ~(size_t)15;
  const size_t partB   = 1024;
  const size_t WtB     = 256 * 128 * sizeof(float);
  const size_t bsB     = 512;
  const size_t smallB  = edgesB + cursorB + rowptrB + partB + WtB + bsB;

  char* base = (char*)d_ws;
  float* agg;
  if (ws_size >= aggB + smallB) {
    agg = (float*)base;
    base += aggB;
  } else {
    agg = out;  // safe fallback: fused_k reads its own tile rows before writing
  }
  int2*  edges   = (int2*)base;               base += edgesB;
  int*   cursor  = (int*)base;                base += cursorB;
  int*   rowptr  = (int*)base;                base += rowptrB;
  int*   partials= (int*)base;                base += partB;
  float* Wt      = (float*)base;              base += WtB;
  float* bs      = (float*)base;

  hipMemsetAsync(cursor, 0, cursorB, stream);
  int eBlocks = (E + 255) / 256;
  hist_k<<<eBlocks, 256, 0, stream>>>(ei, cursor, E);
  scan_block_k<<<NB, 256, 0, stream>>>(cursor, rowptr, partials, Nn);
  scan_partials_k<<<1, 128, 0, stream>>>(partials, NB);
  add_offsets_k<<<(Nn + 255) / 256, 256, 0, stream>>>(rowptr, cursor, partials, Nn, E);
  fill_k<<<eBlocks, 256, 0, stream>>>(ei, ew, cursor, edges, E);

  prep_k<<<128, 256, 0, stream>>>(W1, b1, W2, b2, Wt, bs);

  agg_k<<<(Nn + 3) / 4, 256, 0, stream>>>(x, rowptr, edges, agg, Nn);

  fused_k<<<(Nn + 63) / 64, 256, 0, stream>>>(x, agg, Wt, bs, out, Nn);
}

// Round 5
// 249.484 us; speedup vs baseline: 1.6790x; 1.4118x over previous
//
#include <hip/hip_runtime.h>

#define D 128

typedef __attribute__((ext_vector_type(8))) short short8;
typedef __attribute__((ext_vector_type(4))) float f32x4;

__device__ __forceinline__ unsigned int f2bf(float f) {
  unsigned int u = __float_as_uint(f);
  return (u + 0x7fffu + ((u >> 16) & 1u)) >> 16;   // RNE to bf16
}

// ---------------------------------------------------------------------------
// prep: Bpack = MFMA B-fragment-layout bf16 of Wt[k][j]
//   Wt[k][j] = k<128 ? W1[j][k] : W2[j][k-128]
//   Bpack[((kt*8+nt)*64 + l)*8 + j] = Wt[kt*32 + (l>>4)*8 + j][nt*16 + (l&15)]
// ---------------------------------------------------------------------------
__global__ __launch_bounds__(256) void prep_k(
    const float* __restrict__ W1, const float* __restrict__ b1,
    const float* __restrict__ W2, const float* __restrict__ b2,
    unsigned short* __restrict__ Bpack, float* __restrict__ bsum) {
  int tid = blockIdx.x * 256 + threadIdx.x;   // grid 128 -> 32768
  if (tid < 32768) {
    int j = tid & 7;
    int l = (tid >> 3) & 63;
    int ktnt = tid >> 9;                       // 0..63
    int kt = ktnt >> 3, nt = ktnt & 7;
    int k = kt * 32 + ((l >> 4) << 3) + j;
    int col = nt * 16 + (l & 15);
    float v = (k < 128) ? W1[col * 128 + k] : W2[col * 128 + (k - 128)];
    Bpack[tid] = (unsigned short)f2bf(v);
  }
  if (tid < 128) bsum[tid] = b1[tid] + b2[tid];
}

// ---------------------------------------------------------------------------
// CSR build
// ---------------------------------------------------------------------------
__global__ __launch_bounds__(256) void hist_k(
    const int* __restrict__ ei, int* __restrict__ cursor, int E) {
  int e = blockIdx.x * 256 + threadIdx.x;
  if (e < E) atomicAdd(&cursor[ei[E + e]], 1);
}

__global__ __launch_bounds__(256) void scan_block_k(
    const int* __restrict__ deg, int* __restrict__ rowptr,
    int* __restrict__ partials, int Nn) {
  __shared__ int sdata[256];
  int t = threadIdx.x;
  int base = blockIdx.x * 1024 + t * 4;
  int v[4];
  #pragma unroll
  for (int j = 0; j < 4; ++j) v[j] = (base + j < Nn) ? deg[base + j] : 0;
  int tsum = v[0] + v[1] + v[2] + v[3];
  sdata[t] = tsum;
  __syncthreads();
  for (int off = 1; off < 256; off <<= 1) {
    int add = (t >= off) ? sdata[t - off] : 0;
    __syncthreads();
    sdata[t] += add;
    __syncthreads();
  }
  int run = sdata[t] - tsum;
  if (t == 255) partials[blockIdx.x] = sdata[255];
  #pragma unroll
  for (int j = 0; j < 4; ++j) {
    if (base + j < Nn) rowptr[base + j] = run;
    run += v[j];
  }
}

__global__ __launch_bounds__(128) void scan_partials_k(int* partials, int NB) {
  __shared__ int s[128];
  int t = threadIdx.x;
  int orig = (t < NB) ? partials[t] : 0;
  s[t] = orig;
  __syncthreads();
  for (int off = 1; off < 128; off <<= 1) {
    int add = (t >= off) ? s[t - off] : 0;
    __syncthreads();
    s[t] += add;
    __syncthreads();
  }
  if (t < NB) partials[t] = s[t] - orig;
}

__global__ __launch_bounds__(256) void add_offsets_k(
    int* __restrict__ rowptr, int* __restrict__ cursor,
    const int* __restrict__ partials, int Nn, int E) {
  int i = blockIdx.x * 256 + threadIdx.x;
  if (i < Nn) {
    int v = rowptr[i] + partials[i >> 10];
    rowptr[i] = v;
    cursor[i] = v;
  }
  if (i == 0) rowptr[Nn] = E;
}

__global__ __launch_bounds__(256) void fill_k(
    const int* __restrict__ ei, const float* __restrict__ ew,
    int* __restrict__ cursor, int2* __restrict__ edges, int E) {
  int e = blockIdx.x * 256 + threadIdx.x;
  if (e >= E) return;
  int c = ei[E + e];
  int p = atomicAdd(&cursor[c], 1);
  edges[p] = make_int2(ei[e], __float_as_int(ew[e]));
}

// ---------------------------------------------------------------------------
// x -> bf16 (halves gather traffic in agg_k)
// ---------------------------------------------------------------------------
__global__ __launch_bounds__(256) void xbf_k(
    const float* __restrict__ x, unsigned short* __restrict__ xbf, int n8) {
  int tid = blockIdx.x * 256 + threadIdx.x;
  if (tid >= n8) return;
  float4 a = ((const float4*)x)[(size_t)tid * 2];
  float4 b = ((const float4*)x)[(size_t)tid * 2 + 1];
  uint4 o;
  o.x = f2bf(a.x) | (f2bf(a.y) << 16);
  o.y = f2bf(a.z) | (f2bf(a.w) << 16);
  o.z = f2bf(b.x) | (f2bf(b.y) << 16);
  o.w = f2bf(b.z) | (f2bf(b.w) << 16);
  ((uint4*)xbf)[tid] = o;
}

// ---------------------------------------------------------------------------
// aggregate: one wave per node; two half-waves process interleaved edges
// (lane owns 4 dims as uint2 bf16); __shfl_xor(32) combine at the end.
// 4-deep batch per half = 8 gathers in flight per wave.
// ---------------------------------------------------------------------------
__global__ __launch_bounds__(256) void agg_k(
    const unsigned short* __restrict__ xbf, const int* __restrict__ rowptr,
    const int2* __restrict__ edges, float* __restrict__ agg, int Nn) {
  int node = blockIdx.x * 4 + (threadIdx.x >> 6);
  if (node >= Nn) return;
  int l = threadIdx.x & 63;
  int half = l >> 5, sl = l & 31;
  int beg = rowptr[node], end = rowptr[node + 1];
  float4 acc = make_float4(0.f, 0.f, 0.f, 0.f);
  for (int p = beg + half; p < end; p += 8) {
    int2 e[4];
    #pragma unroll
    for (int i = 0; i < 4; ++i) e[i] = edges[min(p + 2 * i, end - 1)];
    uint2 v[4];
    #pragma unroll
    for (int i = 0; i < 4; ++i)
      v[i] = *(const uint2*)(xbf + (size_t)e[i].x * D + sl * 4);
    #pragma unroll
    for (int i = 0; i < 4; ++i) {
      float w = (p + 2 * i < end) ? __int_as_float(e[i].y) : 0.f;
      acc.x += w * __uint_as_float(v[i].x << 16);
      acc.y += w * __uint_as_float(v[i].x & 0xffff0000u);
      acc.z += w * __uint_as_float(v[i].y << 16);
      acc.w += w * __uint_as_float(v[i].y & 0xffff0000u);
    }
  }
  acc.x += __shfl_xor(acc.x, 32);
  acc.y += __shfl_xor(acc.y, 32);
  acc.z += __shfl_xor(acc.z, 32);
  acc.w += __shfl_xor(acc.w, 32);
  if (half == 0)
    ((float4*)(agg + (size_t)node * D))[sl] = acc;
}

// ---------------------------------------------------------------------------
// fused MFMA: u=agg+x, v=agg*x -> bf16 LDS (64 nodes x 256 k, ROWB=528);
// C[64x128] = U @ Wt via mfma_f32_16x16x32_bf16; bias + leakyrelu.
// Wave w owns nodes [w*16, w*16+16). A row = lane&15, k-chunk = lane>>4.
// C: col = lane&15, row = (lane>>4)*4 + r  (m89-verified layout).
// ---------------------------------------------------------------------------
__global__ __launch_bounds__(256, 4) void fused_k(
    const float* __restrict__ x, const float* __restrict__ agg,
    const unsigned short* __restrict__ Bpack, const float* __restrict__ bsum,
    float* __restrict__ out, int Nn) {
  constexpr int ROWB = 528;                  // 512 B payload + 16 B pad, 16B-aligned
  __shared__ __align__(16) unsigned char Us[64 * ROWB];
  const int t = threadIdx.x;
  const int node0 = blockIdx.x * 64;

  #pragma unroll
  for (int i = 0; i < 8; ++i) {
    int f4 = t + i * 256;                    // 0..2047
    int node = f4 >> 5;
    int d4 = f4 & 31;
    int g = node0 + node;
    float4 a4 = make_float4(0.f, 0.f, 0.f, 0.f), x4 = a4;
    if (g < Nn) {
      a4 = ((const float4*)agg)[(size_t)g * 32 + d4];
      x4 = ((const float4*)x)[(size_t)g * 32 + d4];
    }
    uint2 up, vp;
    up.x = f2bf(a4.x + x4.x) | (f2bf(a4.y + x4.y) << 16);
    up.y = f2bf(a4.z + x4.z) | (f2bf(a4.w + x4.w) << 16);
    vp.x = f2bf(a4.x * x4.x) | (f2bf(a4.y * x4.y) << 16);
    vp.y = f2bf(a4.z * x4.z) | (f2bf(a4.w * x4.w) << 16);
    *(uint2*)(Us + node * ROWB + d4 * 8)       = up;   // u: k 0..127
    *(uint2*)(Us + node * ROWB + 256 + d4 * 8) = vp;   // v: k 128..255
  }
  __syncthreads();

  const int lane = t & 63, w = t >> 6;
  const int c15 = lane & 15, kq = lane >> 4;

  short8 afr[8];
  const unsigned char* abase = Us + (size_t)(w * 16 + c15) * ROWB + kq * 16;
  #pragma unroll
  for (int kt = 0; kt < 8; ++kt)
    afr[kt] = *(const short8*)(abase + kt * 64);

  f32x4 acc[8];
  #pragma unroll
  for (int nt = 0; nt < 8; ++nt) acc[nt] = (f32x4){0.f, 0.f, 0.f, 0.f};

  const short8* bp = (const short8*)Bpack + lane;   // + (kt*8+nt)*64
  #pragma unroll
  for (int kt = 0; kt < 8; ++kt) {
    #pragma unroll
    for (int nt = 0; nt < 8; ++nt) {
      short8 bfr = bp[(kt * 8 + nt) * 64];
      acc[nt] = __builtin_amdgcn_mfma_f32_16x16x32_bf16(afr[kt], bfr, acc[nt], 0, 0, 0);
    }
  }

  float bsv[8];
  #pragma unroll
  for (int nt = 0; nt < 8; ++nt) bsv[nt] = bsum[nt * 16 + c15];

  #pragma unroll
  for (int r = 0; r < 4; ++r) {
    int g = node0 + w * 16 + kq * 4 + r;
    if (g >= Nn) continue;
    float* orow = out + (size_t)g * D + c15;
    #pragma unroll
    for (int nt = 0; nt < 8; ++nt) {
      float h = acc[nt][r] + bsv[nt];
      orow[nt * 16] = h > 0.f ? h : 0.2f * h;
    }
  }
}

// ---------------------------------------------------------------------------
extern "C" void kernel_launch(void* const* d_in, const int* in_sizes, int n_in,
                              void* d_out, int out_size, void* d_ws, size_t ws_size,
                              hipStream_t stream) {
  const float* x  = (const float*)d_in[0];
  const int*   ei = (const int*)d_in[1];
  const float* ew = (const float*)d_in[2];
  const float* W1 = (const float*)d_in[3];
  const float* b1 = (const float*)d_in[4];
  const float* W2 = (const float*)d_in[5];
  const float* b2 = (const float*)d_in[6];
  float* out = (float*)d_out;

  const int Nn = in_sizes[0] / D;   // 100000
  const int E  = in_sizes[2];       // 600000
  const int NB = (Nn + 1023) / 1024;

  const size_t xbfB    = (((size_t)Nn * D * 2) + 255) & ~(size_t)255;
  const size_t edgesB  = (size_t)E * sizeof(int2);
  const size_t cursorB = (((size_t)Nn * 4) + 255) & ~(size_t)255;
  const size_t rowptrB = (((size_t)(Nn + 1) * 4) + 255) & ~(size_t)255;
  const size_t partB   = 1024;
  const size_t BpackB  = 65536;
  const size_t bsB     = 512;
  const size_t aggB    = (size_t)Nn * D * sizeof(float);

  char* base = (char*)d_ws;
  unsigned short* xbf   = (unsigned short*)base;  base += xbfB;
  int2*  edges   = (int2*)base;                   base += edgesB;
  int*   cursor  = (int*)base;                    base += cursorB;
  int*   rowptr  = (int*)base;                    base += rowptrB;
  int*   partials= (int*)base;                    base += partB;
  unsigned short* Bpack = (unsigned short*)base;  base += BpackB;
  float* bs      = (float*)base;                  base += bsB;
  size_t used = (size_t)(base - (char*)d_ws);
  // agg in ws if it fits, else d_out (safe: fused_k reads its own tile's agg
  // rows before overwriting those same rows; __syncthreads separates them)
  float* agg = (ws_size >= used + aggB) ? (float*)base : out;

  hipMemsetAsync(cursor, 0, (size_t)Nn * 4, stream);
  int eBlocks = (E + 255) / 256;
  hist_k<<<eBlocks, 256, 0, stream>>>(ei, cursor, E);
  scan_block_k<<<NB, 256, 0, stream>>>(cursor, rowptr, partials, Nn);
  scan_partials_k<<<1, 128, 0, stream>>>(partials, NB);
  add_offsets_k<<<(Nn + 255) / 256, 256, 0, stream>>>(rowptr, cursor, partials, Nn, E);
  fill_k<<<eBlocks, 256, 0, stream>>>(ei, ew, cursor, edges, E);

  prep_k<<<128, 256, 0, stream>>>(W1, b1, W2, b2, Bpack, bs);

  int n8 = Nn * D / 8;
  xbf_k<<<(n8 + 255) / 256, 256, 0, stream>>>(x, xbf, n8);

  agg_k<<<(Nn + 3) / 4, 256, 0, stream>>>(xbf, rowptr, edges, agg, Nn);

  fused_k<<<(Nn + 63) / 64, 256, 0, stream>>>(x, agg, Bpack, bs, out, Nn);
}